// Round 1
// baseline (302.197 us; speedup 1.0000x reference)
//
#include <hip/hip_runtime.h>
#include <hip/hip_bf16.h>
#include <hip/hip_fp16.h>
#include <stdint.h>

typedef __bf16 bf16_t;
typedef bf16_t bf16x8 __attribute__((ext_vector_type(8)));
typedef bf16_t bf16x4 __attribute__((ext_vector_type(4)));
typedef float f32x4 __attribute__((ext_vector_type(4)));

#define BM 128
#define BN 128
#define BK 32

// async global->LDS, 16B per lane. LDS dst is wave-uniform base + lane*16.
__device__ __forceinline__ void gload_lds16(const void* g, void* l) {
    __builtin_amdgcn_global_load_lds(
        (const __attribute__((address_space(1))) void*)(uintptr_t)g,
        (__attribute__((address_space(3))) void*)(uintptr_t)l,
        16, 0, 0);
}

// ---------------------------------------------------------------------------
// NT GEMM: C[m,n] = scale * sum_k A[m,k]*B[n,k]; A,B bf16 row-major (K contig).
// EPI: 0 = bf16 store, 1 = f16 store (scaled), 2 = f32 store.
// causal_skip: skip blocks entirely above diagonal (n0 > m0+BM-1).
// tri_k: limit K loop to m0+BM (rows only attend to keys < m0+BM).
// ---------------------------------------------------------------------------
template <int EPI>
__global__ __launch_bounds__(256) void gemm_nt(
    const bf16_t* __restrict__ A, long lda, long sAb,
    const bf16_t* __restrict__ B, long ldb, long sBb,
    void* __restrict__ Cv, long ldc, long sCb,
    int K, float scale, int causal_skip, int tri_k)
{
    const int m0 = blockIdx.y * BM;
    const int n0 = blockIdx.x * BN;
    if (causal_skip && n0 > m0 + (BM - 1)) return;
    const int b = blockIdx.z;
    const bf16_t* Ab = A + (size_t)b * sAb;
    const bf16_t* Bb = B + (size_t)b * sBb;
    const int Keff = tri_k ? min(K, m0 + BM) : K;

    __shared__ __align__(16) bf16_t As[BM * BK];
    __shared__ __align__(16) bf16_t Bs[BN * BK];

    const int tid = threadIdx.x;
    const int wid = tid >> 6, lane = tid & 63;
    const int wr = wid >> 1, wc = wid & 1;
    const int hw = lane >> 4, ln = lane & 15;

    // staging: tile is 512 chunks of 16B; thread t covers chunks t and t+256.
    // chunk c -> row c>>2, k-offset (c&3)*8
    const int ar0 = tid >> 2,           ak0 = (tid & 3) * 8;
    const int ar1 = (tid + 256) >> 2,   ak1 = (tid & 3) * 8;

    const bf16_t* Arow0 = Ab + (size_t)(m0 + ar0) * lda + ak0;
    const bf16_t* Arow1 = Ab + (size_t)(m0 + ar1) * lda + ak1;
    const bf16_t* Brow0 = Bb + (size_t)(n0 + ar0) * ldb + ak0;
    const bf16_t* Brow1 = Bb + (size_t)(n0 + ar1) * ldb + ak1;

    f32x4 acc[4][4] = {};

    for (int k0 = 0; k0 < Keff; k0 += BK) {
        gload_lds16(Arow0 + k0, &As[wid * 512]);
        gload_lds16(Arow1 + k0, &As[2048 + wid * 512]);
        gload_lds16(Brow0 + k0, &Bs[wid * 512]);
        gload_lds16(Brow1 + k0, &Bs[2048 + wid * 512]);
        __syncthreads();

        bf16x8 af[4], bfr[4];
#pragma unroll
        for (int t = 0; t < 4; t++) {
            af[t]  = *(const bf16x8*)&As[(wr * 64 + t * 16 + ln) * BK + hw * 8];
            bfr[t] = *(const bf16x8*)&Bs[(wc * 64 + t * 16 + ln) * BK + hw * 8];
        }
#pragma unroll
        for (int ti = 0; ti < 4; ti++)
#pragma unroll
            for (int tj = 0; tj < 4; tj++)
                acc[ti][tj] = __builtin_amdgcn_mfma_f32_16x16x32_bf16(
                    af[ti], bfr[tj], acc[ti][tj], 0, 0, 0);
        __syncthreads();
    }

    // epilogue: C/D layout col=lane&15, row=(lane>>4)*4+reg (m89-verified)
#pragma unroll
    for (int ti = 0; ti < 4; ti++) {
        const int rbase = m0 + wr * 64 + ti * 16 + hw * 4;
#pragma unroll
        for (int tj = 0; tj < 4; tj++) {
            const int col = n0 + wc * 64 + tj * 16 + ln;
#pragma unroll
            for (int rg = 0; rg < 4; rg++) {
                const float v = acc[ti][tj][rg] * scale;
                const size_t idx = (size_t)(rbase + rg) * ldc + col;
                if (EPI == 0) {
                    ((bf16_t*)Cv + (size_t)b * sCb)[idx] = (bf16_t)v;
                } else if (EPI == 1) {
                    ((_Float16*)Cv + (size_t)b * sCb)[idx] = (_Float16)v;
                } else {
                    ((float*)Cv + (size_t)b * sCb)[idx] = v;
                }
            }
        }
    }
}

// ---------------------------------------------------------------------------
__global__ __launch_bounds__(256) void cast_x_kernel(const float* __restrict__ x,
                                                     bf16_t* __restrict__ xb)
{
    const size_t i = ((size_t)blockIdx.x * 256 + threadIdx.x) * 4;
    const float4 v = *(const float4*)(x + i);
    bf16x4 o;
    o.x = (bf16_t)v.x; o.y = (bf16_t)v.y; o.z = (bf16_t)v.z; o.w = (bf16_t)v.w;
    *(bf16x4*)(xb + i) = o;
}

__global__ __launch_bounds__(256) void cast_w_kernel(const float* __restrict__ Wk,
                                                     const float* __restrict__ Wq,
                                                     const float* __restrict__ Wv,
                                                     bf16_t* __restrict__ Wb)
{
    const size_t i = ((size_t)blockIdx.x * 256 + threadIdx.x) * 4;
    const float* src;
    size_t off;
    if (i < (size_t)1048576)      { src = Wk; off = i; }
    else if (i < (size_t)2097152) { src = Wq; off = i - 1048576; }
    else                          { src = Wv; off = i - 2097152; }
    const float4 v = *(const float4*)(src + off);
    bf16x4 o;
    o.x = (bf16_t)v.x; o.y = (bf16_t)v.y; o.z = (bf16_t)v.z; o.w = (bf16_t)v.w;
    *(bf16x4*)(Wb + i) = o;
}

// Vt[b][d][s] = QKVb[b*2048+s][2048+d]
__global__ __launch_bounds__(256) void transpose_v(const bf16_t* __restrict__ QKVb,
                                                   bf16_t* __restrict__ Vt)
{
    __shared__ bf16_t tile[32][33];
    const int b = blockIdx.z;
    const int s0 = blockIdx.x * 32;
    const int d0 = blockIdx.y * 32;
    const int tx = threadIdx.x, ty = threadIdx.y;
#pragma unroll
    for (int k = 0; k < 4; k++) {
        const int s = s0 + ty + k * 8;
        const int d = d0 + tx;
        tile[ty + k * 8][tx] = QKVb[(size_t)(b * 2048 + s) * 3072 + 2048 + d];
    }
    __syncthreads();
#pragma unroll
    for (int k = 0; k < 4; k++) {
        const int d = d0 + ty + k * 8;
        const int s = s0 + tx;
        Vt[(size_t)b * (1024 * 2048) + (size_t)d * 2048 + s] = tile[tx][ty + k * 8];
    }
}

__device__ __forceinline__ float wred_max(float v) {
#pragma unroll
    for (int o = 32; o; o >>= 1) v = fmaxf(v, __shfl_xor(v, o, 64));
    return v;
}
__device__ __forceinline__ float wred_sum(float v) {
#pragma unroll
    for (int o = 32; o; o >>= 1) v += __shfl_xor(v, o, 64);
    return v;
}

// one block per row; reads f16 logits, writes bf16 probs in place (zeros past i)
__global__ __launch_bounds__(256) void softmax_rows(_Float16* __restrict__ S)
{
    __shared__ float red[8];
    const int r = blockIdx.x;
    const int i = r & 2047;
    const int n = i + 1;
    _Float16* row = S + (size_t)r * 2048;
    const int tid = threadIdx.x;
    const int wid = tid >> 6, lane = tid & 63;

    float vals[8];
    float mx = -3e30f;
#pragma unroll
    for (int k = 0; k < 8; k++) {
        const int j = tid + k * 256;
        const float v = (j < n) ? (float)row[j] : -3e30f;
        vals[k] = v;
        mx = fmaxf(mx, v);
    }
    mx = wred_max(mx);
    if (lane == 0) red[wid] = mx;
    __syncthreads();
    mx = fmaxf(fmaxf(red[0], red[1]), fmaxf(red[2], red[3]));

    float s = 0.f;
#pragma unroll
    for (int k = 0; k < 8; k++) {
        const float e = __expf(vals[k] - mx);
        vals[k] = e;
        s += e;
    }
    s = wred_sum(s);
    if (lane == 0) red[4 + wid] = s;
    __syncthreads();
    s = red[4] + red[5] + red[6] + red[7];
    const float inv = 1.0f / s;

    bf16_t* arow = (bf16_t*)row;  // in-place: all reads happened before 1st barrier
#pragma unroll
    for (int k = 0; k < 8; k++) {
        const int j = tid + k * 256;
        arow[j] = (bf16_t)(vals[k] * inv);
    }
}

// ---------------------------------------------------------------------------
extern "C" void kernel_launch(void* const* d_in, const int* in_sizes, int n_in,
                              void* d_out, int out_size, void* d_ws, size_t ws_size,
                              hipStream_t stream)
{
    const float* x  = (const float*)d_in[0];
    const float* Wk = (const float*)d_in[1];
    const float* Wq = (const float*)d_in[2];
    const float* Wv = (const float*)d_in[3];
    char* ws = (char*)d_ws;

    // ws layout (96 MB total):
    //   [0,48)   QKVb bf16 8192x3072 (K | Q | V columns)
    //   [48,64)  Vt   bf16 4 x 1024x2048
    //   [64,80)  xb   bf16 8192x1024   (dead after GEMM1)
    //   [80,86)  Wb   bf16 3072x1024   (dead after GEMM1)
    //   [64,96)  S    f16  4 x 2048x2048 logits -> overwritten in place by bf16 A
    bf16_t*   QKVb = (bf16_t*)(ws);
    bf16_t*   Vt   = (bf16_t*)(ws + ((size_t)48 << 20));
    bf16_t*   xb   = (bf16_t*)(ws + ((size_t)64 << 20));
    bf16_t*   Wb   = (bf16_t*)(ws + ((size_t)80 << 20));
    _Float16* S    = (_Float16*)(ws + ((size_t)64 << 20));
    float*    out  = (float*)d_out;

    cast_x_kernel<<<8192, 256, 0, stream>>>(x, xb);
    cast_w_kernel<<<3072, 256, 0, stream>>>(Wk, Wq, Wv, Wb);

    // GEMM1: QKV = x * Wcat^T  (M=8192, N=3072, K=1024) -> bf16
    gemm_nt<0><<<dim3(24, 64, 1), 256, 0, stream>>>(
        xb, 1024, 0, Wb, 1024, 0, QKVb, 3072, 0, 1024, 1.0f, 0, 0);

    transpose_v<<<dim3(64, 32, 4), dim3(32, 8), 0, stream>>>(QKVb, Vt);

    // GEMM2: S = scale * Q K^T per batch (M=N=2048, K=1024) -> f16, causal skip
    gemm_nt<1><<<dim3(16, 16, 4), 256, 0, stream>>>(
        QKVb + 1024, 3072, 2048L * 3072, QKVb, 3072, 2048L * 3072,
        S, 2048, 2048L * 2048, 1024, 0.03125f, 1, 0);

    softmax_rows<<<8192, 256, 0, stream>>>(S);

    // GEMM3: out = A * Vt^T per batch (M=2048, N=1024, K=2048) -> f32, tri-K
    gemm_nt<2><<<dim3(8, 16, 4), 256, 0, stream>>>(
        (bf16_t*)S, 2048, 2048L * 2048, Vt, 2048, 1024L * 2048,
        out, 1024, 2048L * 1024, 2048, 1.0f, 0, 1);
}

// Round 3
// 285.607 us; speedup vs baseline: 1.0581x; 1.0581x over previous
//
#include <hip/hip_runtime.h>
#include <hip/hip_bf16.h>
#include <hip/hip_fp16.h>
#include <stdint.h>

typedef __bf16 bf16_t;
typedef bf16_t bf16x8 __attribute__((ext_vector_type(8)));
typedef bf16_t bf16x4 __attribute__((ext_vector_type(4)));
typedef float f32x4 __attribute__((ext_vector_type(4)));

#define BM 128
#define BN 128
#define BK 32

// async global->LDS, 16B per lane. LDS dst is wave-uniform base + lane*16.
__device__ __forceinline__ void gload_lds16(const void* g, void* l) {
    __builtin_amdgcn_global_load_lds(
        (const __attribute__((address_space(1))) void*)(uintptr_t)g,
        (__attribute__((address_space(3))) void*)(uintptr_t)l,
        16, 0, 0);
}

// ---------------------------------------------------------------------------
// Shared NT-GEMM body: C[m,n] = scale * sum_k A[m,k]*B[n,k], bf16 inputs.
// EPI: 0 = bf16 store, 1 = f16 store, 2 = f32 store.
// A,B,Cv already batch-offset. Block computes [m0,m0+128) x [n0,n0+128).
// ---------------------------------------------------------------------------
template <int EPI>
__device__ __forceinline__ void gemm_body(
    const bf16_t* __restrict__ A, long lda,
    const bf16_t* __restrict__ B, long ldb,
    void* __restrict__ Cv, long ldc,
    int Keff, float scale, int m0, int n0)
{
    __shared__ __align__(16) bf16_t As[BM * BK];
    __shared__ __align__(16) bf16_t Bs[BN * BK];

    const int tid = threadIdx.x;
    const int wid = tid >> 6, lane = tid & 63;
    const int wr = wid >> 1, wc = wid & 1;
    const int hw = lane >> 4, ln = lane & 15;

    // staging: tile is 512 chunks of 16B; thread t covers chunks t and t+256.
    const int ar0 = tid >> 2,         ak0 = (tid & 3) * 8;
    const int ar1 = (tid + 256) >> 2, ak1 = (tid & 3) * 8;

    const bf16_t* Arow0 = A + (size_t)(m0 + ar0) * lda + ak0;
    const bf16_t* Arow1 = A + (size_t)(m0 + ar1) * lda + ak1;
    const bf16_t* Brow0 = B + (size_t)(n0 + ar0) * ldb + ak0;
    const bf16_t* Brow1 = B + (size_t)(n0 + ar1) * ldb + ak1;

    f32x4 acc[4][4] = {};

    for (int k0 = 0; k0 < Keff; k0 += BK) {
        gload_lds16(Arow0 + k0, &As[wid * 512]);
        gload_lds16(Arow1 + k0, &As[2048 + wid * 512]);
        gload_lds16(Brow0 + k0, &Bs[wid * 512]);
        gload_lds16(Brow1 + k0, &Bs[2048 + wid * 512]);
        __syncthreads();

        bf16x8 af[4], bfr[4];
#pragma unroll
        for (int t = 0; t < 4; t++) {
            af[t]  = *(const bf16x8*)&As[(wr * 64 + t * 16 + ln) * BK + hw * 8];
            bfr[t] = *(const bf16x8*)&Bs[(wc * 64 + t * 16 + ln) * BK + hw * 8];
        }
#pragma unroll
        for (int ti = 0; ti < 4; ti++)
#pragma unroll
            for (int tj = 0; tj < 4; tj++)
                acc[ti][tj] = __builtin_amdgcn_mfma_f32_16x16x32_bf16(
                    af[ti], bfr[tj], acc[ti][tj], 0, 0, 0);
        __syncthreads();
    }

    // epilogue: C/D layout col=lane&15, row=(lane>>4)*4+reg (m89-verified)
#pragma unroll
    for (int ti = 0; ti < 4; ti++) {
        const int rbase = m0 + wr * 64 + ti * 16 + hw * 4;
#pragma unroll
        for (int tj = 0; tj < 4; tj++) {
            const int col = n0 + wc * 64 + tj * 16 + ln;
#pragma unroll
            for (int rg = 0; rg < 4; rg++) {
                const float v = acc[ti][tj][rg] * scale;
                const size_t idx = (size_t)(rbase + rg) * ldc + col;
                if (EPI == 0)      ((bf16_t*)Cv)[idx]   = (bf16_t)v;
                else if (EPI == 1) ((_Float16*)Cv)[idx] = (_Float16)v;
                else               ((float*)Cv)[idx]    = v;
            }
        }
    }
}

// Standalone GEMM kernel (GEMM1, GEMM3). rev_y: dispatch heaviest strips first.
template <int EPI>
__global__ __launch_bounds__(256) void gemm_nt(
    const bf16_t* __restrict__ A, long lda, long sAb,
    const bf16_t* __restrict__ B, long ldb, long sBb,
    void* __restrict__ Cv, long ldc, long sCb,
    int K, float scale, int tri_k, int rev_y)
{
    const int by = rev_y ? (gridDim.y - 1 - blockIdx.y) : blockIdx.y;
    const int m0 = by * BM;
    const int n0 = blockIdx.x * BN;
    const int b = blockIdx.z;
    const int Keff = tri_k ? min(K, m0 + BM) : K;
    const size_t elsz = (EPI == 2) ? 4 : 2;
    gemm_body<EPI>(A + (size_t)b * sAb, lda,
                   B + (size_t)b * sBb, ldb,
                   (char*)Cv + (size_t)b * sCb * elsz, ldc,
                   Keff, scale, m0, n0);
}

// ---------------------------------------------------------------------------
// Merged GEMM2 (causal QK^T -> f16 logits) + V transpose.
// grid (16, 16+128, 4):
//   y <  16  -> gemm block (x, y)
//   y >= 16  -> transpose tile lin=(y-16)*16+x in [0,2048): 64 s-tiles x 32 d-tiles
// ---------------------------------------------------------------------------
__global__ __launch_bounds__(256) void qk_vtrans(
    const bf16_t* __restrict__ QKVb, _Float16* __restrict__ S,
    bf16_t* __restrict__ Vt)
{
    const int b = blockIdx.z;
    if (blockIdx.y < 16) {
        const int m0 = blockIdx.y * BM;
        const int n0 = blockIdx.x * BN;
        if (n0 > m0 + (BM - 1)) return;  // fully above diagonal
        const bf16_t* Qb = QKVb + 1024 + (size_t)b * (2048L * 3072);
        const bf16_t* Kb = QKVb + (size_t)b * (2048L * 3072);
        _Float16* Sb = S + (size_t)b * (2048L * 2048);
        gemm_body<1>(Qb, 3072, Kb, 3072, Sb, 2048, 1024, 0.03125f, m0, n0);
    } else {
        __shared__ bf16_t ttile[32][33];
        const int lin = (blockIdx.y - 16) * 16 + blockIdx.x;  // 0..2047
        const int s0 = (lin & 63) * 32;        // 64 s-tiles
        const int d0 = (lin >> 6) * 32;        // 32 d-tiles (d < 1024)
        const int tx = threadIdx.x & 31, ty = threadIdx.x >> 5;  // 32x8
#pragma unroll
        for (int k = 0; k < 4; k++) {
            const int s = s0 + ty + k * 8;
            const int d = d0 + tx;
            ttile[ty + k * 8][tx] = QKVb[(size_t)(b * 2048 + s) * 3072 + 2048 + d];
        }
        __syncthreads();
#pragma unroll
        for (int k = 0; k < 4; k++) {
            const int d = d0 + ty + k * 8;
            const int s = s0 + tx;
            Vt[(size_t)b * (1024 * 2048) + (size_t)d * 2048 + s] = ttile[tx][ty + k * 8];
        }
    }
}

// ---------------------------------------------------------------------------
// Merged input casts: blocks [0,8192) cast x (8M f32), [8192,11264) cast W (3M).
__global__ __launch_bounds__(256) void cast_all(
    const float* __restrict__ x,
    const float* __restrict__ Wk, const float* __restrict__ Wq,
    const float* __restrict__ Wv,
    bf16_t* __restrict__ xb, bf16_t* __restrict__ Wb)
{
    const int blk = blockIdx.x;
    const float* src;
    bf16_t* dst;
    if (blk < 8192) {
        const size_t i = ((size_t)blk * 256 + threadIdx.x) * 4;
        src = x + i;
        dst = xb + i;
    } else {
        const size_t j = ((size_t)(blk - 8192) * 256 + threadIdx.x) * 4;
        dst = Wb + j;
        if (j < (size_t)1048576)      src = Wk + j;
        else if (j < (size_t)2097152) src = Wq + (j - 1048576);
        else                          src = Wv + (j - 2097152);
    }
    const float4 v = *(const float4*)src;
    bf16x4 o;
    o.x = (bf16_t)v.x; o.y = (bf16_t)v.y; o.z = (bf16_t)v.z; o.w = (bf16_t)v.w;
    *(bf16x4*)dst = o;
}

__device__ __forceinline__ float wred_max(float v) {
#pragma unroll
    for (int o = 32; o; o >>= 1) v = fmaxf(v, __shfl_xor(v, o, 64));
    return v;
}
__device__ __forceinline__ float wred_sum(float v) {
#pragma unroll
    for (int o = 32; o; o >>= 1) v += __shfl_xor(v, o, 64);
    return v;
}

// one block per row; reads f16 logits, writes bf16 probs in place (zeros past i)
__global__ __launch_bounds__(256) void softmax_rows(_Float16* __restrict__ S)
{
    __shared__ float red[8];
    const int r = blockIdx.x;
    const int i = r & 2047;
    const int n = i + 1;
    _Float16* row = S + (size_t)r * 2048;
    const int tid = threadIdx.x;
    const int wid = tid >> 6, lane = tid & 63;

    float vals[8];
    float mx = -3e30f;
#pragma unroll
    for (int k = 0; k < 8; k++) {
        const int j = tid + k * 256;
        const float v = (j < n) ? (float)row[j] : -3e30f;
        vals[k] = v;
        mx = fmaxf(mx, v);
    }
    mx = wred_max(mx);
    if (lane == 0) red[wid] = mx;
    __syncthreads();
    mx = fmaxf(fmaxf(red[0], red[1]), fmaxf(red[2], red[3]));

    float s = 0.f;
#pragma unroll
    for (int k = 0; k < 8; k++) {
        const float e = __expf(vals[k] - mx);
        vals[k] = e;
        s += e;
    }
    s = wred_sum(s);
    if (lane == 0) red[4 + wid] = s;
    __syncthreads();
    s = red[4] + red[5] + red[6] + red[7];
    const float inv = 1.0f / s;

    bf16_t* arow = (bf16_t*)row;  // in-place: all reads happened before 1st barrier
#pragma unroll
    for (int k = 0; k < 8; k++) {
        const int j = tid + k * 256;
        arow[j] = (bf16_t)(vals[k] * inv);
    }
}

// ---------------------------------------------------------------------------
extern "C" void kernel_launch(void* const* d_in, const int* in_sizes, int n_in,
                              void* d_out, int out_size, void* d_ws, size_t ws_size,
                              hipStream_t stream)
{
    const float* x  = (const float*)d_in[0];
    const float* Wk = (const float*)d_in[1];
    const float* Wq = (const float*)d_in[2];
    const float* Wv = (const float*)d_in[3];
    char* ws = (char*)d_ws;

    // ws layout (96 MB total):
    //   [0,48)   QKVb bf16 8192x3072 (K | Q | V columns)
    //   [48,64)  Vt   bf16 4 x 1024x2048
    //   [64,80)  xb   bf16 8192x1024   (dead after GEMM1)
    //   [80,86)  Wb   bf16 3072x1024   (dead after GEMM1)
    //   [64,96)  S    f16  4 x 2048x2048 logits -> overwritten in place by bf16 A
    bf16_t*   QKVb = (bf16_t*)(ws);
    bf16_t*   Vt   = (bf16_t*)(ws + ((size_t)48 << 20));
    bf16_t*   xb   = (bf16_t*)(ws + ((size_t)64 << 20));
    bf16_t*   Wb   = (bf16_t*)(ws + ((size_t)80 << 20));
    _Float16* S    = (_Float16*)(ws + ((size_t)64 << 20));
    float*    out  = (float*)d_out;

    // 1. cast inputs to bf16
    cast_all<<<11264, 256, 0, stream>>>(x, Wk, Wq, Wv, xb, Wb);

    // 2. GEMM1: QKV = x * Wcat^T  (M=8192, N=3072, K=1024) -> bf16
    gemm_nt<0><<<dim3(24, 64, 1), 256, 0, stream>>>(
        xb, 1024, 0, Wb, 1024, 0, QKVb, 3072, 0, 1024, 1.0f, 0, 0);

    // 3. GEMM2 (causal QK^T -> f16 logits) + V transpose, one launch
    qk_vtrans<<<dim3(16, 16 + 128, 4), 256, 0, stream>>>(QKVb, S, Vt);

    // 4. softmax rows (f16 logits -> bf16 probs in place)
    softmax_rows<<<8192, 256, 0, stream>>>(S);

    // 5. GEMM3: out = A * Vt^T per batch (M=2048, N=1024, K=2048) -> f32,
    //    tri-K, heaviest strips dispatched first (rev_y)
    gemm_nt<2><<<dim3(8, 16, 4), 256, 0, stream>>>(
        (bf16_t*)S, 2048, 2048L * 2048, Vt, 2048, 1024L * 2048,
        out, 1024, 2048L * 1024, 2048, 1.0f, 1, 1);
}

// Round 4
// 279.876 us; speedup vs baseline: 1.0798x; 1.0205x over previous
//
#include <hip/hip_runtime.h>
#include <hip/hip_bf16.h>
#include <hip/hip_fp16.h>
#include <stdint.h>

typedef __bf16 bf16_t;
typedef bf16_t bf16x8 __attribute__((ext_vector_type(8)));
typedef bf16_t bf16x4 __attribute__((ext_vector_type(4)));
typedef _Float16 f16x8 __attribute__((ext_vector_type(8)));
typedef float f32x4 __attribute__((ext_vector_type(4)));

#define BM 128
#define BN 128
#define BK 32

// async global->LDS, 16B per lane. LDS dst is wave-uniform base + lane*16.
__device__ __forceinline__ void gload_lds16(const void* g, void* l) {
    __builtin_amdgcn_global_load_lds(
        (const __attribute__((address_space(1))) void*)(uintptr_t)g,
        (__attribute__((address_space(3))) void*)(uintptr_t)l,
        16, 0, 0);
}

// ---------------------------------------------------------------------------
// Shared NT-GEMM body: C[m,n] = scale * sum_{k0<=k<k1} A[m,k]*B[n,k].
// EPI: 0 = bf16 store, 1 = f16 store, 2 = f32 store (atomicAdd if use_atomic).
// A,B,Cv already batch-offset. Block computes [m0,m0+128) x [n0,n0+128).
// ---------------------------------------------------------------------------
template <int EPI>
__device__ __forceinline__ void gemm_body(
    const bf16_t* __restrict__ A, long lda,
    const bf16_t* __restrict__ B, long ldb,
    void* __restrict__ Cv, long ldc,
    int k0beg, int k1end, float scale, int m0, int n0, int use_atomic)
{
    __shared__ __align__(16) bf16_t As[BM * BK];
    __shared__ __align__(16) bf16_t Bs[BN * BK];

    const int tid = threadIdx.x;
    const int wid = tid >> 6, lane = tid & 63;
    const int wr = wid >> 1, wc = wid & 1;
    const int hw = lane >> 4, ln = lane & 15;

    // staging: tile is 512 chunks of 16B; thread t covers chunks t and t+256.
    const int ar0 = tid >> 2,         ak0 = (tid & 3) * 8;
    const int ar1 = (tid + 256) >> 2, ak1 = (tid & 3) * 8;

    const bf16_t* Arow0 = A + (size_t)(m0 + ar0) * lda + ak0;
    const bf16_t* Arow1 = A + (size_t)(m0 + ar1) * lda + ak1;
    const bf16_t* Brow0 = B + (size_t)(n0 + ar0) * ldb + ak0;
    const bf16_t* Brow1 = B + (size_t)(n0 + ar1) * ldb + ak1;

    f32x4 acc[4][4] = {};

    for (int k0 = k0beg; k0 < k1end; k0 += BK) {
        gload_lds16(Arow0 + k0, &As[wid * 512]);
        gload_lds16(Arow1 + k0, &As[2048 + wid * 512]);
        gload_lds16(Brow0 + k0, &Bs[wid * 512]);
        gload_lds16(Brow1 + k0, &Bs[2048 + wid * 512]);
        __syncthreads();

        bf16x8 af[4], bfr[4];
#pragma unroll
        for (int t = 0; t < 4; t++) {
            af[t]  = *(const bf16x8*)&As[(wr * 64 + t * 16 + ln) * BK + hw * 8];
            bfr[t] = *(const bf16x8*)&Bs[(wc * 64 + t * 16 + ln) * BK + hw * 8];
        }
#pragma unroll
        for (int ti = 0; ti < 4; ti++)
#pragma unroll
            for (int tj = 0; tj < 4; tj++)
                acc[ti][tj] = __builtin_amdgcn_mfma_f32_16x16x32_bf16(
                    af[ti], bfr[tj], acc[ti][tj], 0, 0, 0);
        __syncthreads();
    }

    // epilogue: C/D layout col=lane&15, row=(lane>>4)*4+reg (m89-verified)
#pragma unroll
    for (int ti = 0; ti < 4; ti++) {
        const int rbase = m0 + wr * 64 + ti * 16 + hw * 4;
#pragma unroll
        for (int tj = 0; tj < 4; tj++) {
            const int col = n0 + wc * 64 + tj * 16 + ln;
#pragma unroll
            for (int rg = 0; rg < 4; rg++) {
                const float v = acc[ti][tj][rg] * scale;
                const size_t idx = (size_t)(rbase + rg) * ldc + col;
                if (EPI == 0)      ((bf16_t*)Cv)[idx]   = (bf16_t)v;
                else if (EPI == 1) ((_Float16*)Cv)[idx] = (_Float16)v;
                else {
                    if (use_atomic) atomicAdd(&((float*)Cv)[idx], v);
                    else            ((float*)Cv)[idx] = v;
                }
            }
        }
    }
}

// ---------------------------------------------------------------------------
// GEMM1: QKV = x * Wcat^T (M=8192, N=3072, K=1024) -> bf16.
// Supertile swizzle: 8m x 8n supertiles (~4MB A+B footprint) for XCD-L2 reuse.
// grid (24, 64).
// ---------------------------------------------------------------------------
__global__ __launch_bounds__(256) void gemm1_qkv(
    const bf16_t* __restrict__ xb, const bf16_t* __restrict__ Wb,
    bf16_t* __restrict__ QKVb)
{
    const int lin = blockIdx.y * 24 + blockIdx.x;   // 0..1535
    const int s = lin >> 6, w = lin & 63;           // 24 supertiles of 64
    const int mblk = (s & 7) * 8 + (w >> 3);        // 0..63
    const int nblk = (s >> 3) * 8 + (w & 7);        // 0..23
    gemm_body<0>(xb, 1024, Wb, 1024, QKVb, 3072,
                 0, 1024, 1.0f, mblk * BM, nblk * BN, 0);
}

// ---------------------------------------------------------------------------
// Merged GEMM2 (causal QK^T -> f16 logits) + V transpose.
// grid (16, 16+128, 4):
//   y <  16  -> gemm block (x, y)
//   y >= 16  -> transpose tile lin=(y-16)*16+x in [0,2048): 64 s-tiles x 32 d-tiles
// ---------------------------------------------------------------------------
__global__ __launch_bounds__(256) void qk_vtrans(
    const bf16_t* __restrict__ QKVb, _Float16* __restrict__ S,
    bf16_t* __restrict__ Vt)
{
    const int b = blockIdx.z;
    if (blockIdx.y < 16) {
        const int m0 = blockIdx.y * BM;
        const int n0 = blockIdx.x * BN;
        if (n0 > m0 + (BM - 1)) return;  // fully above diagonal
        const bf16_t* Qb = QKVb + 1024 + (size_t)b * (2048L * 3072);
        const bf16_t* Kb = QKVb + (size_t)b * (2048L * 3072);
        _Float16* Sb = S + (size_t)b * (2048L * 2048);
        gemm_body<1>(Qb, 3072, Kb, 3072, Sb, 2048, 0, 1024, 0.03125f, m0, n0, 0);
    } else {
        __shared__ bf16_t ttile[32][33];
        const int lin = (blockIdx.y - 16) * 16 + blockIdx.x;  // 0..2047
        const int s0 = (lin & 63) * 32;        // 64 s-tiles
        const int d0 = (lin >> 6) * 32;        // 32 d-tiles (d < 1024)
        const int tx = threadIdx.x & 31, ty = threadIdx.x >> 5;  // 32x8
#pragma unroll
        for (int k = 0; k < 4; k++) {
            const int s = s0 + ty + k * 8;
            const int d = d0 + tx;
            ttile[ty + k * 8][tx] = QKVb[(size_t)(b * 2048 + s) * 3072 + 2048 + d];
        }
        __syncthreads();
#pragma unroll
        for (int k = 0; k < 4; k++) {
            const int d = d0 + ty + k * 8;
            const int s = s0 + tx;
            Vt[(size_t)b * (1024 * 2048) + (size_t)d * 2048 + s] = ttile[tx][ty + k * 8];
        }
    }
}

// ---------------------------------------------------------------------------
// GEMM3: out = P * Vt^T per batch (M=2048, N=1024, K<=2048) -> f32.
// Split-K: 24 chunks/batch-col; strips 8..15 split at K=1024 (both halves
// atomicAdd into zeroed out); strips 0..7 single-chunk plain store.
// Heavy chunks (32 iters) dispatch first via cmap. grid (8, 24, 4).
// ---------------------------------------------------------------------------
__global__ __launch_bounds__(256) void gemm3_pv(
    const bf16_t* __restrict__ P, const bf16_t* __restrict__ Vt,
    float* __restrict__ out)
{
    static const int cmap[24] = {8, 9, 10, 11, 12, 13, 14, 15, 7, 23, 6, 22,
                                 5, 21, 4, 20, 3, 19, 2, 18, 1, 17, 0, 16};
    const int c = cmap[blockIdx.y];
    const int b = blockIdx.z;
    const int n0 = blockIdx.x * BN;
    int m0, k0, k1, at;
    if (c < 16) {            // first (or only) chunk of strip c
        m0 = c * 128; k0 = 0; k1 = min(m0 + 128, 1024); at = (c >= 8);
    } else {                 // second chunk of strip c-8
        m0 = (c - 8) * 128; k0 = 1024; k1 = m0 + 128; at = 1;
    }
    gemm_body<2>(P + (size_t)b * (2048L * 2048), 2048,
                 Vt + (size_t)b * (1024L * 2048), 2048,
                 out + (size_t)b * (2048L * 1024), 1024,
                 k0, k1, 1.0f, m0, n0, at);
}

// ---------------------------------------------------------------------------
// Merged input casts: blocks [0,8192) cast x (8M f32), [8192,11264) cast W (3M).
__global__ __launch_bounds__(256) void cast_all(
    const float* __restrict__ x,
    const float* __restrict__ Wk, const float* __restrict__ Wq,
    const float* __restrict__ Wv,
    bf16_t* __restrict__ xb, bf16_t* __restrict__ Wb)
{
    const int blk = blockIdx.x;
    const float* src;
    bf16_t* dst;
    if (blk < 8192) {
        const size_t i = ((size_t)blk * 256 + threadIdx.x) * 4;
        src = x + i;
        dst = xb + i;
    } else {
        const size_t j = ((size_t)(blk - 8192) * 256 + threadIdx.x) * 4;
        dst = Wb + j;
        if (j < (size_t)1048576)      src = Wk + j;
        else if (j < (size_t)2097152) src = Wq + (j - 1048576);
        else                          src = Wv + (j - 2097152);
    }
    const float4 v = *(const float4*)src;
    bf16x4 o;
    o.x = (bf16_t)v.x; o.y = (bf16_t)v.y; o.z = (bf16_t)v.z; o.w = (bf16_t)v.w;
    *(bf16x4*)dst = o;
}

__device__ __forceinline__ float wred_max(float v) {
#pragma unroll
    for (int o = 32; o; o >>= 1) v = fmaxf(v, __shfl_xor(v, o, 64));
    return v;
}
__device__ __forceinline__ float wred_sum(float v) {
#pragma unroll
    for (int o = 32; o; o >>= 1) v += __shfl_xor(v, o, 64);
    return v;
}

// one block per row; vectorized 16B loads/stores. f16 logits -> bf16 probs
// in place (cols > i produce garbage-masked -inf -> 0 prob).
__global__ __launch_bounds__(256) void softmax_rows(_Float16* __restrict__ S)
{
    __shared__ float red[8];
    const int r = blockIdx.x;
    const int i = r & 2047;
    const int n = i + 1;
    _Float16* row = S + (size_t)r * 2048;
    const int tid = threadIdx.x;
    const int wid = tid >> 6, lane = tid & 63;
    const int base = tid * 8;

    const f16x8 v8 = *(const f16x8*)(row + base);
    float vals[8];
    float mx = -3e30f;
#pragma unroll
    for (int k = 0; k < 8; k++) {
        const float v = (base + k < n) ? (float)v8[k] : -3e30f;
        vals[k] = v;
        mx = fmaxf(mx, v);
    }
    mx = wred_max(mx);
    if (lane == 0) red[wid] = mx;
    __syncthreads();
    mx = fmaxf(fmaxf(red[0], red[1]), fmaxf(red[2], red[3]));

    float s = 0.f;
#pragma unroll
    for (int k = 0; k < 8; k++) {
        const float e = __expf(vals[k] - mx);
        vals[k] = e;
        s += e;
    }
    s = wred_sum(s);
    if (lane == 0) red[4 + wid] = s;
    __syncthreads();
    s = red[4] + red[5] + red[6] + red[7];
    const float inv = 1.0f / s;

    bf16x8 o;
#pragma unroll
    for (int k = 0; k < 8; k++) o[k] = (bf16_t)(vals[k] * inv);
    *(bf16x8*)((bf16_t*)row + base) = o;
}

// ---------------------------------------------------------------------------
extern "C" void kernel_launch(void* const* d_in, const int* in_sizes, int n_in,
                              void* d_out, int out_size, void* d_ws, size_t ws_size,
                              hipStream_t stream)
{
    const float* x  = (const float*)d_in[0];
    const float* Wk = (const float*)d_in[1];
    const float* Wq = (const float*)d_in[2];
    const float* Wv = (const float*)d_in[3];
    char* ws = (char*)d_ws;

    // ws layout (96 MB total):
    //   [0,48)   QKVb bf16 8192x3072 (K | Q | V columns)
    //   [48,64)  Vt   bf16 4 x 1024x2048
    //   [64,80)  xb   bf16 8192x1024   (dead after GEMM1)
    //   [80,86)  Wb   bf16 3072x1024   (dead after GEMM1)
    //   [64,96)  S    f16  4 x 2048x2048 logits -> overwritten in place by bf16 P
    bf16_t*   QKVb = (bf16_t*)(ws);
    bf16_t*   Vt   = (bf16_t*)(ws + ((size_t)48 << 20));
    bf16_t*   xb   = (bf16_t*)(ws + ((size_t)64 << 20));
    bf16_t*   Wb   = (bf16_t*)(ws + ((size_t)80 << 20));
    _Float16* S    = (_Float16*)(ws + ((size_t)64 << 20));
    float*    out  = (float*)d_out;

    // zero d_out for GEMM3's split-K atomic accumulation
    hipMemsetAsync(d_out, 0, (size_t)out_size * 4, stream);

    // 1. cast inputs to bf16
    cast_all<<<11264, 256, 0, stream>>>(x, Wk, Wq, Wv, xb, Wb);

    // 2. GEMM1 (L2-swizzled)
    gemm1_qkv<<<dim3(24, 64, 1), 256, 0, stream>>>(xb, Wb, QKVb);

    // 3. GEMM2 (causal QK^T -> f16 logits) + V transpose, one launch
    qk_vtrans<<<dim3(16, 16 + 128, 4), 256, 0, stream>>>(QKVb, S, Vt);

    // 4. softmax rows (f16 logits -> bf16 probs in place)
    softmax_rows<<<8192, 256, 0, stream>>>(S);

    // 5. GEMM3 split-K with atomic f32 accumulation
    gemm3_pv<<<dim3(8, 24, 4), 256, 0, stream>>>((bf16_t*)S, Vt, out);
}

// Round 5
// 243.539 us; speedup vs baseline: 1.2409x; 1.1492x over previous
//
#include <hip/hip_runtime.h>
#include <hip/hip_bf16.h>
#include <hip/hip_fp16.h>
#include <stdint.h>

typedef __bf16 bf16_t;
typedef bf16_t bf16x8 __attribute__((ext_vector_type(8)));
typedef bf16_t bf16x4 __attribute__((ext_vector_type(4)));
typedef _Float16 f16x8 __attribute__((ext_vector_type(8)));
typedef float f32x4 __attribute__((ext_vector_type(4)));

#define BM 128
#define BN 128
#define BK 32

// async global->LDS, 16B per lane. LDS dst is wave-uniform base + lane*16.
__device__ __forceinline__ void gload_lds16(const void* g, void* l) {
    __builtin_amdgcn_global_load_lds(
        (const __attribute__((address_space(1))) void*)(uintptr_t)g,
        (__attribute__((address_space(3))) void*)(uintptr_t)l,
        16, 0, 0);
}

// ---------------------------------------------------------------------------
// Shared NT-GEMM body: C[m,n] = scale * sum_{k0beg<=k<k1end} A[m,k]*B[n,k].
// EPI: 0 = bf16 store, 1 = f16 store, 2 = f32 store.
// A,B,Cv already batch-offset. Block computes [m0,m0+128) x [n0,n0+128).
// ---------------------------------------------------------------------------
template <int EPI>
__device__ __forceinline__ void gemm_body(
    const bf16_t* __restrict__ A, long lda,
    const bf16_t* __restrict__ B, long ldb,
    void* __restrict__ Cv, long ldc,
    int k0beg, int k1end, float scale, int m0, int n0)
{
    __shared__ __align__(16) bf16_t As[BM * BK];
    __shared__ __align__(16) bf16_t Bs[BN * BK];

    const int tid = threadIdx.x;
    const int wid = tid >> 6, lane = tid & 63;
    const int wr = wid >> 1, wc = wid & 1;
    const int hw = lane >> 4, ln = lane & 15;

    // staging: tile is 512 chunks of 16B; thread t covers chunks t and t+256.
    const int ar0 = tid >> 2,         ak0 = (tid & 3) * 8;
    const int ar1 = (tid + 256) >> 2, ak1 = (tid & 3) * 8;

    const bf16_t* Arow0 = A + (size_t)(m0 + ar0) * lda + ak0;
    const bf16_t* Arow1 = A + (size_t)(m0 + ar1) * lda + ak1;
    const bf16_t* Brow0 = B + (size_t)(n0 + ar0) * ldb + ak0;
    const bf16_t* Brow1 = B + (size_t)(n0 + ar1) * ldb + ak1;

    f32x4 acc[4][4] = {};

    for (int k0 = k0beg; k0 < k1end; k0 += BK) {
        gload_lds16(Arow0 + k0, &As[wid * 512]);
        gload_lds16(Arow1 + k0, &As[2048 + wid * 512]);
        gload_lds16(Brow0 + k0, &Bs[wid * 512]);
        gload_lds16(Brow1 + k0, &Bs[2048 + wid * 512]);
        __syncthreads();

        bf16x8 af[4], bfr[4];
#pragma unroll
        for (int t = 0; t < 4; t++) {
            af[t]  = *(const bf16x8*)&As[(wr * 64 + t * 16 + ln) * BK + hw * 8];
            bfr[t] = *(const bf16x8*)&Bs[(wc * 64 + t * 16 + ln) * BK + hw * 8];
        }
#pragma unroll
        for (int ti = 0; ti < 4; ti++)
#pragma unroll
            for (int tj = 0; tj < 4; tj++)
                acc[ti][tj] = __builtin_amdgcn_mfma_f32_16x16x32_bf16(
                    af[ti], bfr[tj], acc[ti][tj], 0, 0, 0);
        __syncthreads();
    }

    // epilogue: C/D layout col=lane&15, row=(lane>>4)*4+reg (m89-verified)
#pragma unroll
    for (int ti = 0; ti < 4; ti++) {
        const int rbase = m0 + wr * 64 + ti * 16 + hw * 4;
#pragma unroll
        for (int tj = 0; tj < 4; tj++) {
            const int col = n0 + wc * 64 + tj * 16 + ln;
#pragma unroll
            for (int rg = 0; rg < 4; rg++) {
                const float v = acc[ti][tj][rg] * scale;
                const size_t idx = (size_t)(rbase + rg) * ldc + col;
                if (EPI == 0)      ((bf16_t*)Cv)[idx]   = (bf16_t)v;
                else if (EPI == 1) ((_Float16*)Cv)[idx] = (_Float16)v;
                else               ((float*)Cv)[idx]    = v;
            }
        }
    }
}

// ---------------------------------------------------------------------------
// GEMM1: QKV = x * Wcat^T (M=8192, N=3072, K=1024) -> bf16.  grid 1536 (1-D).
// XCD-pinned swizzle (dispatch is round-robin over 8 XCDs):
//   xcd  = lin & 7      -> owns m-blocks [8*xcd, 8*xcd+8)  (A slice 2 MB in L2)
//   p    = (lin>>3)>>6  -> n-phase, nblks [8p, 8p+8)       (B slice 2 MB, L3-shared)
//   w    = (lin>>3)&63  -> position in 8x8 supertile
// Per-phase L2 footprint = 4 MB = one XCD L2; A reused across all 3 phases.
// ---------------------------------------------------------------------------
__global__ __launch_bounds__(256) void gemm1_qkv(
    const bf16_t* __restrict__ xb, const bf16_t* __restrict__ Wb,
    bf16_t* __restrict__ QKVb)
{
    const int lin = blockIdx.x;            // 0..1535
    const int xcd = lin & 7;
    const int j   = lin >> 3;              // 0..191
    const int p   = j >> 6;                // 0..2
    const int w   = j & 63;                // 0..63
    const int mblk = xcd * 8 + (w >> 3);   // 0..63
    const int nblk = p * 8 + (w & 7);      // 0..23
    gemm_body<0>(xb, 1024, Wb, 1024, QKVb, 3072,
                 0, 1024, 1.0f, mblk * BM, nblk * BN);
}

// ---------------------------------------------------------------------------
// Merged GEMM2 (causal QK^T -> f16 logits) + V transpose. grid 9216 (1-D).
//   id < 1024 : gemm block. g=id>>2 (b=id&3 fastest): my=15-(g>>4) heavy-first,
//               nx=g&15. Skip if fully above diagonal.
//   id >= 1024: transpose tile t=id-1024: b=t>>11, lin=t&2047 ->
//               s0=(lin&63)*32, d0=(lin>>6)*32.
// ---------------------------------------------------------------------------
__global__ __launch_bounds__(256) void qk_vtrans(
    const bf16_t* __restrict__ QKVb, _Float16* __restrict__ S,
    bf16_t* __restrict__ Vt)
{
    const int id = blockIdx.x;
    if (id < 1024) {
        const int b  = id & 3;
        const int g  = id >> 2;
        const int my = 15 - (g >> 4);      // heavy strips first
        const int nx = g & 15;
        const int m0 = my * BM, n0 = nx * BN;
        if (n0 > m0 + (BM - 1)) return;    // fully above diagonal
        const bf16_t* Qb = QKVb + 1024 + (size_t)b * (2048L * 3072);
        const bf16_t* Kb = QKVb + (size_t)b * (2048L * 3072);
        _Float16* Sb = S + (size_t)b * (2048L * 2048);
        gemm_body<1>(Qb, 3072, Kb, 3072, Sb, 2048, 0, 1024, 0.03125f, m0, n0);
    } else {
        __shared__ bf16_t ttile[32][33];
        const int t = id - 1024;           // 0..8191
        const int b = t >> 11;
        const int lin = t & 2047;
        const int s0 = (lin & 63) * 32;
        const int d0 = (lin >> 6) * 32;
        const int tx = threadIdx.x & 31, ty = threadIdx.x >> 5;  // 32x8
#pragma unroll
        for (int k = 0; k < 4; k++) {
            const int s = s0 + ty + k * 8;
            const int d = d0 + tx;
            ttile[ty + k * 8][tx] = QKVb[(size_t)(b * 2048 + s) * 3072 + 2048 + d];
        }
        __syncthreads();
#pragma unroll
        for (int k = 0; k < 4; k++) {
            const int d = d0 + ty + k * 8;
            const int s = s0 + tx;
            Vt[(size_t)b * (1024 * 2048) + (size_t)d * 2048 + s] = ttile[tx][ty + k * 8];
        }
    }
}

// ---------------------------------------------------------------------------
// GEMM3: out = P * Vt^T per batch (M=2048, N=1024, K=m0+128 tri) -> f32.
// grid 512 (1-D), heavy strips first, batch fastest-varying:
//   strip = 15 - (id>>5), nx = (id>>2)&7, b = id&3.
// ---------------------------------------------------------------------------
__global__ __launch_bounds__(256) void gemm3_pv(
    const bf16_t* __restrict__ P, const bf16_t* __restrict__ Vt,
    float* __restrict__ out)
{
    const int id = blockIdx.x;
    const int strip = 15 - (id >> 5);
    const int nx = (id >> 2) & 7;
    const int b = id & 3;
    const int m0 = strip * BM;
    const int Keff = m0 + BM;              // causal: rows attend keys < m0+128
    gemm_body<2>(P + (size_t)b * (2048L * 2048), 2048,
                 Vt + (size_t)b * (1024L * 2048), 2048,
                 out + (size_t)b * (2048L * 1024), 1024,
                 0, Keff, 1.0f, m0, nx * BN);
}

// ---------------------------------------------------------------------------
// Merged input casts: blocks [0,8192) cast x (8M f32), [8192,11264) cast W (3M).
__global__ __launch_bounds__(256) void cast_all(
    const float* __restrict__ x,
    const float* __restrict__ Wk, const float* __restrict__ Wq,
    const float* __restrict__ Wv,
    bf16_t* __restrict__ xb, bf16_t* __restrict__ Wb)
{
    const int blk = blockIdx.x;
    const float* src;
    bf16_t* dst;
    if (blk < 8192) {
        const size_t i = ((size_t)blk * 256 + threadIdx.x) * 4;
        src = x + i;
        dst = xb + i;
    } else {
        const size_t j = ((size_t)(blk - 8192) * 256 + threadIdx.x) * 4;
        dst = Wb + j;
        if (j < (size_t)1048576)      src = Wk + j;
        else if (j < (size_t)2097152) src = Wq + (j - 1048576);
        else                          src = Wv + (j - 2097152);
    }
    const float4 v = *(const float4*)src;
    bf16x4 o;
    o.x = (bf16_t)v.x; o.y = (bf16_t)v.y; o.z = (bf16_t)v.z; o.w = (bf16_t)v.w;
    *(bf16x4*)dst = o;
}

__device__ __forceinline__ float wred_max(float v) {
#pragma unroll
    for (int o = 32; o; o >>= 1) v = fmaxf(v, __shfl_xor(v, o, 64));
    return v;
}
__device__ __forceinline__ float wred_sum(float v) {
#pragma unroll
    for (int o = 32; o; o >>= 1) v += __shfl_xor(v, o, 64);
    return v;
}

// one block per row; vectorized 16B loads/stores. f16 logits -> bf16 probs
// in place (cols > i masked to -inf -> 0 prob).
__global__ __launch_bounds__(256) void softmax_rows(_Float16* __restrict__ S)
{
    __shared__ float red[8];
    const int r = blockIdx.x;
    const int i = r & 2047;
    const int n = i + 1;
    _Float16* row = S + (size_t)r * 2048;
    const int tid = threadIdx.x;
    const int wid = tid >> 6, lane = tid & 63;
    const int base = tid * 8;

    const f16x8 v8 = *(const f16x8*)(row + base);
    float vals[8];
    float mx = -3e30f;
#pragma unroll
    for (int k = 0; k < 8; k++) {
        const float v = (base + k < n) ? (float)v8[k] : -3e30f;
        vals[k] = v;
        mx = fmaxf(mx, v);
    }
    mx = wred_max(mx);
    if (lane == 0) red[wid] = mx;
    __syncthreads();
    mx = fmaxf(fmaxf(red[0], red[1]), fmaxf(red[2], red[3]));

    float s = 0.f;
#pragma unroll
    for (int k = 0; k < 8; k++) {
        const float e = __expf(vals[k] - mx);
        vals[k] = e;
        s += e;
    }
    s = wred_sum(s);
    if (lane == 0) red[4 + wid] = s;
    __syncthreads();
    s = red[4] + red[5] + red[6] + red[7];
    const float inv = 1.0f / s;

    bf16x8 o;
#pragma unroll
    for (int k = 0; k < 8; k++) o[k] = (bf16_t)(vals[k] * inv);
    *(bf16x8*)((bf16_t*)row + base) = o;
}

// ---------------------------------------------------------------------------
extern "C" void kernel_launch(void* const* d_in, const int* in_sizes, int n_in,
                              void* d_out, int out_size, void* d_ws, size_t ws_size,
                              hipStream_t stream)
{
    const float* x  = (const float*)d_in[0];
    const float* Wk = (const float*)d_in[1];
    const float* Wq = (const float*)d_in[2];
    const float* Wv = (const float*)d_in[3];
    char* ws = (char*)d_ws;

    // ws layout (96 MB total):
    //   [0,48)   QKVb bf16 8192x3072 (K | Q | V columns)
    //   [48,64)  Vt   bf16 4 x 1024x2048
    //   [64,80)  xb   bf16 8192x1024   (dead after GEMM1)
    //   [80,86)  Wb   bf16 3072x1024   (dead after GEMM1)
    //   [64,96)  S    f16  4 x 2048x2048 logits -> overwritten in place by bf16 P
    bf16_t*   QKVb = (bf16_t*)(ws);
    bf16_t*   Vt   = (bf16_t*)(ws + ((size_t)48 << 20));
    bf16_t*   xb   = (bf16_t*)(ws + ((size_t)64 << 20));
    bf16_t*   Wb   = (bf16_t*)(ws + ((size_t)80 << 20));
    _Float16* S    = (_Float16*)(ws + ((size_t)64 << 20));
    float*    out  = (float*)d_out;

    // 1. cast inputs to bf16
    cast_all<<<11264, 256, 0, stream>>>(x, Wk, Wq, Wv, xb, Wb);

    // 2. GEMM1 (XCD-pinned supertile swizzle)
    gemm1_qkv<<<1536, 256, 0, stream>>>(xb, Wb, QKVb);

    // 3. GEMM2 (causal QK^T -> f16 logits, heavy-first) + V transpose
    qk_vtrans<<<9216, 256, 0, stream>>>(QKVb, S, Vt);

    // 4. softmax rows (f16 logits -> bf16 probs in place)
    softmax_rows<<<8192, 256, 0, stream>>>(S);

    // 5. GEMM3 tri-K, heavy-first, plain f32 stores
    gemm3_pv<<<512, 256, 0, stream>>>((bf16_t*)S, Vt, out);
}